// Round 10
// baseline (112.805 us; speedup 1.0000x reference)
//
#include <hip/hip_runtime.h>

#define NN 4096
#define FIN 256
#define CC 256
#define NH 8
#define NW32 (NN / 32)  // u32 words per adj row

typedef __attribute__((ext_vector_type(8))) short short8;
typedef __attribute__((ext_vector_type(4))) float f32x4;
typedef __attribute__((ext_vector_type(4))) unsigned int u32x4;

__device__ __forceinline__ unsigned cvtpk_bf16(float lo, float hi) {
  unsigned r;
  asm("v_cvt_pk_bf16_f32 %0, %1, %2" : "=v"(r) : "v"(lo), "v"(hi));
  return r;
}

__device__ __forceinline__ unsigned short bf16rn(float x) {
  unsigned int u = __builtin_bit_cast(unsigned int, x);
  u += 0x7fffu + ((u >> 16) & 1u);
  return (unsigned short)(u >> 16);
}

__device__ __forceinline__ void gl_lds16(const void* g, void* l) {
  __builtin_amdgcn_global_load_lds(
      (const __attribute__((address_space(1))) void*)g,
      (__attribute__((address_space(3))) void*)l, 16, 0, 0);
}

// ---------------- K1: adj bitpack (ballot) + g = h@W fused epilogue --------
// adjb[i][w] bit e = adj[i][w*32+e]!=0  (j-ordered via wave ballot).
// gTs: chunk-major SWIZZLED bf16 (unit 16B at [jc][c][p], p = q ^ ((c>>1)&3)).
// spack[h][n] = (e^s_src, e^{0.2 s_src}, 0, 0).
// dtc[jc][2][NH][32] = (e^sd, e^{0.2 sd}).
#define GROWS 8
__global__ __launch_bounds__(256) void k_gemm(
    const float* __restrict__ h, const float* __restrict__ W,
    const float* __restrict__ a, const int* __restrict__ adj,
    unsigned int* __restrict__ adjb, unsigned short* __restrict__ gTs,
    float4* __restrict__ spack, float* __restrict__ dtc) {
  __shared__ float hs[GROWS][FIN];
  const int t = threadIdx.x;
  const int lane = t & 63, w = t >> 6;

  // --- bitpack 8 adj rows: coalesced dword loads + j-ordered ballot
  {
    const int rbase = blockIdx.x * 8;
#pragma unroll
    for (int r = 0; r < 2; ++r) {
      const int row = rbase + w * 2 + r;
      const int* src = adj + (size_t)row * NN;
      unsigned long long* dst = (unsigned long long*)(adjb + (size_t)row * NW32);
#pragma unroll 4
      for (int g = 0; g < 64; ++g) {
        const int v = src[g * 64 + lane];
        const unsigned long long b = __ballot(v != 0);
        if (lane == 0) dst[g] = b;
      }
    }
  }

  // --- GEMM
  const int r0 = blockIdx.x * GROWS;
#pragma unroll
  for (int idx = t; idx < GROWS * FIN / 4; idx += 256) {
    const int r = idx >> 6, c4 = idx & 63;
    *(float4*)&hs[r][c4 * 4] =
        *(const float4*)&h[(size_t)(r0 + r) * FIN + c4 * 4];
  }
  __syncthreads();
  const int c = t;
  float acc[GROWS];
#pragma unroll
  for (int r = 0; r < GROWS; ++r) acc[r] = 0.f;
  for (int k = 0; k < FIN; k += 4) {
    const float w0 = W[(size_t)(k + 0) * CC + c];
    const float w1 = W[(size_t)(k + 1) * CC + c];
    const float w2 = W[(size_t)(k + 2) * CC + c];
    const float w3 = W[(size_t)(k + 3) * CC + c];
#pragma unroll
    for (int r = 0; r < GROWS; ++r) {
      const float4 hv = *(const float4*)&hs[r][k];
      acc[r] += hv.x * w0 + hv.y * w1 + hv.z * w2 + hv.w * w3;
    }
  }
  const int f = c & 31, hh = c >> 5;
  const float aS = a[f], aD = a[32 + f];
  unsigned short gu[GROWS];
#pragma unroll
  for (int r = 0; r < GROWS; ++r) {
    float ps = acc[r] * aS, pd = acc[r] * aD;
#pragma unroll
    for (int m = 1; m < 32; m <<= 1) {
      ps += __shfl_xor(ps, m, 64);
      pd += __shfl_xor(pd, m, 64);
    }
    if (f == 0) {
      const int n = r0 + r;
      spack[(size_t)hh * NN + n] =
          make_float4(__expf(ps), __expf(0.2f * ps), 0.f, 0.f);
      float* dc = dtc + (size_t)(n >> 5) * 512 + hh * 32 + (n & 31);
      dc[0] = __expf(pd);
      dc[256] = __expf(0.2f * pd);
    }
    gu[r] = bf16rn(acc[r]);
  }
  uint4 gv;
  gv.x = (unsigned)gu[0] | ((unsigned)gu[1] << 16);
  gv.y = (unsigned)gu[2] | ((unsigned)gu[3] << 16);
  gv.z = (unsigned)gu[4] | ((unsigned)gu[5] << 16);
  gv.w = (unsigned)gu[6] | ((unsigned)gu[7] << 16);
  const int jc = r0 >> 5, qq = (r0 >> 3) & 3;
  const int p = qq ^ ((c >> 1) & 3);
  *(uint4*)(gTs + ((size_t)jc * 1024 + c * 4 + p) * 8) = gv;
}

// ---------------- K2: LDS 2-phase fused masked-softmax + MFMA PV -----------
// Block = 32 i x 8 heads; 4 waves: wave w -> head-pair {2w,2w+1}.
// e^leaky(ss+sd) = max(e^ss*e^sd, e^{0.2ss}*e^{0.2sd})  (exact identity).
struct Buf {
  unsigned short gt[8192];  // 16 KB swizzled: unit u = c*4 + (q ^ ((c>>1)&3))
  float dt[2][NH][32];      // 2 KB: (e^sd, e^{0.2sd})
};

__global__ __launch_bounds__(256, 4) void k_attn(
    const unsigned int* __restrict__ adjb, const unsigned short* __restrict__ gTs,
    const float4* __restrict__ spack, const float* __restrict__ dtc,
    float* __restrict__ acc_ws, float* __restrict__ l_ws,
    float* __restrict__ out, const int splits, const int direct) {
  __shared__ Buf buf[2];  // 36 KB

  const int lane = threadIdx.x & 63;
  const int w = threadIdx.x >> 6;
  const int il = lane & 15, q = lane >> 4;
  const int bx = blockIdx.x;
  const int sp = bx & (splits - 1);
  const int ib = bx / splits;
  const int i0 = ib * 32;
  const int hbase = w * 2;
  const int jrange = NN / splits, j0b = sp * jrange;
  const int c0 = j0b >> 5;

  // hoisted i-side scalars (2 heads x 2 it)
  float e1v[2][2], e2v[2][2];
#pragma unroll
  for (int hp = 0; hp < 2; ++hp)
#pragma unroll
    for (int it = 0; it < 2; ++it) {
      const float4 v = spack[(size_t)(hbase + hp) * NN + i0 + it * 16 + il];
      e1v[hp][it] = v.x; e2v[hp][it] = v.y;
    }

  f32x4 acc[2][2][2];
  f32x4 lac[2][2];
#pragma unroll
  for (int hp = 0; hp < 2; ++hp)
#pragma unroll
    for (int it = 0; it < 2; ++it) {
#pragma unroll
      for (int r = 0; r < 4; ++r) lac[hp][it][r] = 0.f;
#pragma unroll
      for (int ft = 0; ft < 2; ++ft)
#pragma unroll
        for (int r = 0; r < 4; ++r) acc[hp][it][ft][r] = 0.f;
    }

  const short8 ones = {(short)0x3F80, (short)0x3F80, (short)0x3F80,
                       (short)0x3F80, (short)0x3F80, (short)0x3F80,
                       (short)0x3F80, (short)0x3F80};

  const unsigned int* ab0 = adjb + (size_t)(i0 + il) * NW32 + (j0b >> 5);
  const unsigned int* ab1 = adjb + (size_t)(i0 + 16 + il) * NW32 + (j0b >> 5);
  const int sh = q * 8;
  const int pswz = q ^ ((il >> 1) & 3);

  // ---- staging: linear copies (gTs pre-swizzled in global) ----
  auto stage = [&](Buf* b, int jc) {
    const unsigned short* src = gTs + (size_t)(c0 + jc) * 8192;
#pragma unroll
    for (int pass = 0; pass < 4; ++pass) {
      const int base = pass * 256 + w * 64;  // wave-uniform
      gl_lds16(src + (size_t)(base + lane) * 8, (char*)b->gt + base * 16);
    }
    if (w < 2) {
      const float* dsrc = dtc + (size_t)(c0 + jc) * 512;
      gl_lds16(dsrc + (size_t)(w * 64 + lane) * 4,
               (char*)&b->dt[0][0][0] + (w * 64) * 16);
    }
  };

  const int nch = jrange / 32;
  stage(&buf[0], 0);
  unsigned int pb0 = ab0[0], pb1 = ab1[0];
  __syncthreads();
  int cur = 0;

  for (int jc = 0; jc < nch; ++jc) {
    if (jc + 1 < nch) stage(&buf[cur ^ 1], jc + 1);
    const Buf* bc = &buf[cur];

    float adf[2][8];
    {
      const unsigned int bits0 = pb0, bits1 = pb1;
#pragma unroll
      for (int e = 0; e < 8; ++e) {
        adf[0][e] = (float)((bits0 >> (sh + e)) & 1u);
        adf[1][e] = (float)((bits1 >> (sh + e)) & 1u);
      }
      if (jc + 1 < nch) { pb0 = ab0[jc + 1]; pb1 = ab1[jc + 1]; }
    }

#pragma unroll
    for (int hp = 0; hp < 2; ++hp) {
      const int hh = hbase + hp;
      float e1j[8], e2j[8];
      *(float4*)&e1j[0] = *(const float4*)&bc->dt[0][hh][q * 8];
      *(float4*)&e1j[4] = *(const float4*)&bc->dt[0][hh][q * 8 + 4];
      *(float4*)&e2j[0] = *(const float4*)&bc->dt[1][hh][q * 8];
      *(float4*)&e2j[4] = *(const float4*)&bc->dt[1][hh][q * 8 + 4];
      const int u0 = (hh * 32 + il) * 4 + pswz;
      const short8 b0 = *(const short8*)&bc->gt[u0 * 8];
      const short8 b1 = *(const short8*)&bc->gt[(u0 + 64) * 8];
#pragma unroll
      for (int it = 0; it < 2; ++it) {
        const float ei1 = e1v[hp][it], ei2 = e2v[hp][it];
        float wv[8];
#pragma unroll
        for (int e = 0; e < 8; ++e)
          wv[e] = fmaxf(ei1 * e1j[e], ei2 * e2j[e]) * adf[it][e];
        u32x4 uu;
#pragma unroll
        for (int m = 0; m < 4; ++m)
          uu[m] = cvtpk_bf16(wv[2 * m], wv[2 * m + 1]);
        const short8 afr = __builtin_bit_cast(short8, uu);
        acc[hp][it][0] = __builtin_amdgcn_mfma_f32_16x16x32_bf16(
            afr, b0, acc[hp][it][0], 0, 0, 0);
        acc[hp][it][1] = __builtin_amdgcn_mfma_f32_16x16x32_bf16(
            afr, b1, acc[hp][it][1], 0, 0, 0);
        lac[hp][it] = __builtin_amdgcn_mfma_f32_16x16x32_bf16(
            afr, ones, lac[hp][it], 0, 0, 0);
      }
    }
    __syncthreads();  // drains staging vmcnt + read lgkm; swap safe
    cur ^= 1;
  }

  if (direct) {
#pragma unroll
    for (int hp = 0; hp < 2; ++hp) {
      const int hh = hbase + hp;
#pragma unroll
      for (int it = 0; it < 2; ++it)
#pragma unroll
        for (int r = 0; r < 4; ++r) {
          const float inv = 1.f / lac[hp][it][r];
          const size_t irow = i0 + it * 16 + q * 4 + r;
#pragma unroll
          for (int ft = 0; ft < 2; ++ft)
            out[irow * CC + hh * 32 + ft * 16 + il] =
                acc[hp][it][ft][r] * inv;
        }
    }
  } else {
#pragma unroll
    for (int hp = 0; hp < 2; ++hp) {
      const int hh = hbase + hp;
#pragma unroll
      for (int it = 0; it < 2; ++it)
#pragma unroll
        for (int r = 0; r < 4; ++r) {
          const size_t irow = i0 + it * 16 + q * 4 + r;
          if (il == 0)
            l_ws[((size_t)sp * NH + hh) * NN + irow] = lac[hp][it][r];
#pragma unroll
          for (int ft = 0; ft < 2; ++ft)
            acc_ws[((size_t)sp * NN + irow) * CC + hh * 32 + ft * 16 + il] =
                acc[hp][it][ft][r];
        }
    }
  }
}

// ---------------- K3: combine split partials ----------------
__global__ __launch_bounds__(256) void k_combine(
    const float* __restrict__ acc_ws, const float* __restrict__ l_ws,
    float* __restrict__ out, const int splits) {
  const int idx = blockIdx.x * 256 + threadIdx.x;  // float4 index
  const int row = idx >> 6, c4 = idx & 63;
  const int hh = c4 >> 3;
  float ax = 0.f, ay = 0.f, az = 0.f, aw = 0.f, l = 0.f;
  for (int s = 0; s < splits; ++s) {
    const float4 v =
        *(const float4*)&acc_ws[((size_t)s * NN + row) * CC + c4 * 4];
    ax += v.x; ay += v.y; az += v.z; aw += v.w;
    l += l_ws[((size_t)s * NH + hh) * NN + row];
  }
  const float inv = 1.f / l;
  *(float4*)&out[(size_t)row * CC + c4 * 4] =
      make_float4(ax * inv, ay * inv, az * inv, aw * inv);
}

extern "C" void kernel_launch(void* const* d_in, const int* in_sizes, int n_in,
                              void* d_out, int out_size, void* d_ws,
                              size_t ws_size, hipStream_t stream) {
  (void)in_sizes; (void)n_in; (void)out_size;
  const float* h = (const float*)d_in[0];
  const int* adj = (const int*)d_in[1];
  const float* W = (const float*)d_in[2];
  const float* a = (const float*)d_in[3];
  float* out = (float*)d_out;
  char* ws = (char*)d_ws;

  unsigned short* gTs = (unsigned short*)ws;               // 2 MB (swizzled)
  float4* spack = (float4*)(ws + (size_t)NN * CC * 2);     // 512 KB
  float* dtc = (float*)(spack + (size_t)NH * NN);          // 256 KB (2 planes)
  unsigned int* adjb =
      (unsigned int*)(dtc + (size_t)(NN / 32) * 512);      // 2 MB
  char* after = (char*)(adjb + (size_t)NN * NW32);
  const size_t base = (size_t)(after - ws);
  const size_t per_split = (size_t)NN * CC * 4 + (size_t)NH * NN * 4;

  int splits = 1;
  if (ws_size >= base + 8 * per_split) splits = 8;
  else if (ws_size >= base + 4 * per_split) splits = 4;
  else if (ws_size >= base + 2 * per_split) splits = 2;

  k_gemm<<<NN / GROWS, 256, 0, stream>>>(h, W, a, adj, adjb, gTs, spack, dtc);

  const int nblk = (NN / 32) * splits;
  if (splits == 1) {
    k_attn<<<nblk, 256, 0, stream>>>(adjb, gTs, spack, dtc, nullptr, nullptr,
                                     out, 1, 1);
  } else {
    float* acc_ws = (float*)after;
    float* l_ws = acc_ws + (size_t)splits * NN * CC;
    k_attn<<<nblk, 256, 0, stream>>>(adjb, gTs, spack, dtc, acc_ws, l_ws, out,
                                     splits, 0);
    k_combine<<<NN * CC / 4 / 256, 256, 0, stream>>>(acc_ws, l_ws, out,
                                                     splits);
  }
}

// Round 11
// 87.709 us; speedup vs baseline: 1.2861x; 1.2861x over previous
//
#include <hip/hip_runtime.h>

#define NN 4096
#define FIN 256
#define CC 256
#define NH 8
#define NW32 (NN / 32)  // u32 words per adj row

typedef __attribute__((ext_vector_type(8))) short short8;
typedef __attribute__((ext_vector_type(4))) float f32x4;
typedef __attribute__((ext_vector_type(4))) unsigned int u32x4;

__device__ __forceinline__ unsigned cvtpk_bf16(float lo, float hi) {
  unsigned r;
  asm("v_cvt_pk_bf16_f32 %0, %1, %2" : "=v"(r) : "v"(lo), "v"(hi));
  return r;
}

__device__ __forceinline__ unsigned short bf16rn(float x) {
  unsigned int u = __builtin_bit_cast(unsigned int, x);
  u += 0x7fffu + ((u >> 16) & 1u);
  return (unsigned short)(u >> 16);
}

__device__ __forceinline__ void gl_lds16(const void* g, void* l) {
  __builtin_amdgcn_global_load_lds(
      (const __attribute__((address_space(1))) void*)g,
      (__attribute__((address_space(3))) void*)l, 16, 0, 0);
}

// ---------------- K1: fused {GEMM+epilogue | adj bitpack} by block range ---
// blocks [0,512): GEMM g=h@W, write swizzled gTs + spack + dtc.
// blocks [512, 512+2048): bitpack — thread => one u32 word (32 contiguous
//   adj ints, 128 B) via 8 independent int4 loads (ILP=8, streaming).
// adjb[i][w] bit e = adj[i][w*32+e]!=0.
// gTs: chunk-major SWIZZLED bf16 (unit 16B at [jc][c][p], p = q ^ ((c>>1)&3)).
// spack[h][n] = (e^s_src, e^{0.2 s_src}, 0, 0).
// dtc[jc][2][NH][32] = (e^sd, e^{0.2 sd}).
#define GROWS 8
#define GEMM_BLKS (NN / GROWS)                  // 512
#define BP_BLKS (NN * NW32 / 256)               // 2048
__global__ __launch_bounds__(256) void k_gemm(
    const float* __restrict__ h, const float* __restrict__ W,
    const float* __restrict__ a, const int* __restrict__ adj,
    unsigned int* __restrict__ adjb, unsigned short* __restrict__ gTs,
    float4* __restrict__ spack, float* __restrict__ dtc) {
  __shared__ float hs[GROWS][FIN];
  const int t = threadIdx.x;
  const int bx = blockIdx.x;

  if (bx >= GEMM_BLKS) {
    // ---- bitpack path: one word per thread, 8x int4 streaming loads ----
    const int wid = (bx - GEMM_BLKS) * 256 + t;  // word index
    const int row = wid >> 7, wd = wid & 127;
    const int* src = adj + (size_t)row * NN + wd * 32;
    int4 v[8];
#pragma unroll
    for (int s = 0; s < 8; ++s) v[s] = *(const int4*)&src[s * 4];
    unsigned int bits = 0;
#pragma unroll
    for (int s = 0; s < 8; ++s) {
      bits |= (v[s].x ? 1u : 0u) << (s * 4 + 0);
      bits |= (v[s].y ? 1u : 0u) << (s * 4 + 1);
      bits |= (v[s].z ? 1u : 0u) << (s * 4 + 2);
      bits |= (v[s].w ? 1u : 0u) << (s * 4 + 3);
    }
    adjb[(size_t)row * NW32 + wd] = bits;
    return;
  }

  // ---- GEMM path ----
  const int r0 = bx * GROWS;
#pragma unroll
  for (int idx = t; idx < GROWS * FIN / 4; idx += 256) {
    const int r = idx >> 6, c4 = idx & 63;
    *(float4*)&hs[r][c4 * 4] =
        *(const float4*)&h[(size_t)(r0 + r) * FIN + c4 * 4];
  }
  __syncthreads();
  const int c = t;
  float acc[GROWS];
#pragma unroll
  for (int r = 0; r < GROWS; ++r) acc[r] = 0.f;
  for (int k = 0; k < FIN; k += 4) {
    const float w0 = W[(size_t)(k + 0) * CC + c];
    const float w1 = W[(size_t)(k + 1) * CC + c];
    const float w2 = W[(size_t)(k + 2) * CC + c];
    const float w3 = W[(size_t)(k + 3) * CC + c];
#pragma unroll
    for (int r = 0; r < GROWS; ++r) {
      const float4 hv = *(const float4*)&hs[r][k];
      acc[r] += hv.x * w0 + hv.y * w1 + hv.z * w2 + hv.w * w3;
    }
  }
  const int f = c & 31, hh = c >> 5;
  const float aS = a[f], aD = a[32 + f];
  unsigned short gu[GROWS];
#pragma unroll
  for (int r = 0; r < GROWS; ++r) {
    float ps = acc[r] * aS, pd = acc[r] * aD;
#pragma unroll
    for (int m = 1; m < 32; m <<= 1) {
      ps += __shfl_xor(ps, m, 64);
      pd += __shfl_xor(pd, m, 64);
    }
    if (f == 0) {
      const int n = r0 + r;
      spack[(size_t)hh * NN + n] =
          make_float4(__expf(ps), __expf(0.2f * ps), 0.f, 0.f);
      float* dc = dtc + (size_t)(n >> 5) * 512 + hh * 32 + (n & 31);
      dc[0] = __expf(pd);
      dc[256] = __expf(0.2f * pd);
    }
    gu[r] = bf16rn(acc[r]);
  }
  uint4 gv;
  gv.x = (unsigned)gu[0] | ((unsigned)gu[1] << 16);
  gv.y = (unsigned)gu[2] | ((unsigned)gu[3] << 16);
  gv.z = (unsigned)gu[4] | ((unsigned)gu[5] << 16);
  gv.w = (unsigned)gu[6] | ((unsigned)gu[7] << 16);
  const int jc = r0 >> 5, qq = (r0 >> 3) & 3;
  const int p = qq ^ ((c >> 1) & 3);
  *(uint4*)(gTs + ((size_t)jc * 1024 + c * 4 + p) * 8) = gv;
}

// ---------------- K2: LDS 2-phase fused masked-softmax + MFMA PV -----------
// Block = 32 i x 8 heads; 4 waves: wave w -> head-pair {2w,2w+1}.
// e^leaky(ss+sd) = max(e^ss*e^sd, e^{0.2ss}*e^{0.2sd})  (exact identity).
struct Buf {
  unsigned short gt[8192];  // 16 KB swizzled: unit u = c*4 + (q ^ ((c>>1)&3))
  float dt[2][NH][32];      // 2 KB: (e^sd, e^{0.2sd})
};

__global__ __launch_bounds__(256, 4) void k_attn(
    const unsigned int* __restrict__ adjb, const unsigned short* __restrict__ gTs,
    const float4* __restrict__ spack, const float* __restrict__ dtc,
    float* __restrict__ acc_ws, float* __restrict__ l_ws,
    float* __restrict__ out, const int splits, const int direct) {
  __shared__ Buf buf[2];  // 36 KB

  const int lane = threadIdx.x & 63;
  const int w = threadIdx.x >> 6;
  const int il = lane & 15, q = lane >> 4;
  const int bx = blockIdx.x;
  const int sp = bx & (splits - 1);
  const int ib = bx / splits;
  const int i0 = ib * 32;
  const int hbase = w * 2;
  const int jrange = NN / splits, j0b = sp * jrange;
  const int c0 = j0b >> 5;

  // hoisted i-side scalars (2 heads x 2 it)
  float e1v[2][2], e2v[2][2];
#pragma unroll
  for (int hp = 0; hp < 2; ++hp)
#pragma unroll
    for (int it = 0; it < 2; ++it) {
      const float4 v = spack[(size_t)(hbase + hp) * NN + i0 + it * 16 + il];
      e1v[hp][it] = v.x; e2v[hp][it] = v.y;
    }

  f32x4 acc[2][2][2];
  f32x4 lac[2][2];
#pragma unroll
  for (int hp = 0; hp < 2; ++hp)
#pragma unroll
    for (int it = 0; it < 2; ++it) {
#pragma unroll
      for (int r = 0; r < 4; ++r) lac[hp][it][r] = 0.f;
#pragma unroll
      for (int ft = 0; ft < 2; ++ft)
#pragma unroll
        for (int r = 0; r < 4; ++r) acc[hp][it][ft][r] = 0.f;
    }

  const short8 ones = {(short)0x3F80, (short)0x3F80, (short)0x3F80,
                       (short)0x3F80, (short)0x3F80, (short)0x3F80,
                       (short)0x3F80, (short)0x3F80};

  const unsigned int* ab0 = adjb + (size_t)(i0 + il) * NW32 + (j0b >> 5);
  const unsigned int* ab1 = adjb + (size_t)(i0 + 16 + il) * NW32 + (j0b >> 5);
  const int sh = q * 8;
  const int pswz = q ^ ((il >> 1) & 3);

  // ---- staging: linear copies (gTs pre-swizzled in global) ----
  auto stage = [&](Buf* b, int jc) {
    const unsigned short* src = gTs + (size_t)(c0 + jc) * 8192;
#pragma unroll
    for (int pass = 0; pass < 4; ++pass) {
      const int base = pass * 256 + w * 64;  // wave-uniform
      gl_lds16(src + (size_t)(base + lane) * 8, (char*)b->gt + base * 16);
    }
    if (w < 2) {
      const float* dsrc = dtc + (size_t)(c0 + jc) * 512;
      gl_lds16(dsrc + (size_t)(w * 64 + lane) * 4,
               (char*)&b->dt[0][0][0] + (w * 64) * 16);
    }
  };

  const int nch = jrange / 32;
  stage(&buf[0], 0);
  unsigned int pb0 = ab0[0], pb1 = ab1[0];
  __syncthreads();
  int cur = 0;

  for (int jc = 0; jc < nch; ++jc) {
    if (jc + 1 < nch) stage(&buf[cur ^ 1], jc + 1);
    const Buf* bc = &buf[cur];

    float adf[2][8];
    {
      const unsigned int bits0 = pb0, bits1 = pb1;
#pragma unroll
      for (int e = 0; e < 8; ++e) {
        adf[0][e] = (float)((bits0 >> (sh + e)) & 1u);
        adf[1][e] = (float)((bits1 >> (sh + e)) & 1u);
      }
      if (jc + 1 < nch) { pb0 = ab0[jc + 1]; pb1 = ab1[jc + 1]; }
    }

#pragma unroll
    for (int hp = 0; hp < 2; ++hp) {
      const int hh = hbase + hp;
      float e1j[8], e2j[8];
      *(float4*)&e1j[0] = *(const float4*)&bc->dt[0][hh][q * 8];
      *(float4*)&e1j[4] = *(const float4*)&bc->dt[0][hh][q * 8 + 4];
      *(float4*)&e2j[0] = *(const float4*)&bc->dt[1][hh][q * 8];
      *(float4*)&e2j[4] = *(const float4*)&bc->dt[1][hh][q * 8 + 4];
      const int u0 = (hh * 32 + il) * 4 + pswz;
      const short8 b0 = *(const short8*)&bc->gt[u0 * 8];
      const short8 b1 = *(const short8*)&bc->gt[(u0 + 64) * 8];
#pragma unroll
      for (int it = 0; it < 2; ++it) {
        const float ei1 = e1v[hp][it], ei2 = e2v[hp][it];
        float wv[8];
#pragma unroll
        for (int e = 0; e < 8; ++e)
          wv[e] = fmaxf(ei1 * e1j[e], ei2 * e2j[e]) * adf[it][e];
        u32x4 uu;
#pragma unroll
        for (int m = 0; m < 4; ++m)
          uu[m] = cvtpk_bf16(wv[2 * m], wv[2 * m + 1]);
        const short8 afr = __builtin_bit_cast(short8, uu);
        acc[hp][it][0] = __builtin_amdgcn_mfma_f32_16x16x32_bf16(
            afr, b0, acc[hp][it][0], 0, 0, 0);
        acc[hp][it][1] = __builtin_amdgcn_mfma_f32_16x16x32_bf16(
            afr, b1, acc[hp][it][1], 0, 0, 0);
        lac[hp][it] = __builtin_amdgcn_mfma_f32_16x16x32_bf16(
            afr, ones, lac[hp][it], 0, 0, 0);
      }
    }
    __syncthreads();  // drains staging vmcnt + read lgkm; swap safe
    cur ^= 1;
  }

  if (direct) {
#pragma unroll
    for (int hp = 0; hp < 2; ++hp) {
      const int hh = hbase + hp;
#pragma unroll
      for (int it = 0; it < 2; ++it)
#pragma unroll
        for (int r = 0; r < 4; ++r) {
          const float inv = 1.f / lac[hp][it][r];
          const size_t irow = i0 + it * 16 + q * 4 + r;
#pragma unroll
          for (int ft = 0; ft < 2; ++ft)
            out[irow * CC + hh * 32 + ft * 16 + il] =
                acc[hp][it][ft][r] * inv;
        }
    }
  } else {
#pragma unroll
    for (int hp = 0; hp < 2; ++hp) {
      const int hh = hbase + hp;
#pragma unroll
      for (int it = 0; it < 2; ++it)
#pragma unroll
        for (int r = 0; r < 4; ++r) {
          const size_t irow = i0 + it * 16 + q * 4 + r;
          if (il == 0)
            l_ws[((size_t)sp * NH + hh) * NN + irow] = lac[hp][it][r];
#pragma unroll
          for (int ft = 0; ft < 2; ++ft)
            acc_ws[((size_t)sp * NN + irow) * CC + hh * 32 + ft * 16 + il] =
                acc[hp][it][ft][r];
        }
    }
  }
}

// ---------------- K3: combine split partials ----------------
__global__ __launch_bounds__(256) void k_combine(
    const float* __restrict__ acc_ws, const float* __restrict__ l_ws,
    float* __restrict__ out, const int splits) {
  const int idx = blockIdx.x * 256 + threadIdx.x;  // float4 index
  const int row = idx >> 6, c4 = idx & 63;
  const int hh = c4 >> 3;
  float ax = 0.f, ay = 0.f, az = 0.f, aw = 0.f, l = 0.f;
  for (int s = 0; s < splits; ++s) {
    const float4 v =
        *(const float4*)&acc_ws[((size_t)s * NN + row) * CC + c4 * 4];
    ax += v.x; ay += v.y; az += v.z; aw += v.w;
    l += l_ws[((size_t)s * NH + hh) * NN + row];
  }
  const float inv = 1.f / l;
  *(float4*)&out[(size_t)row * CC + c4 * 4] =
      make_float4(ax * inv, ay * inv, az * inv, aw * inv);
}

extern "C" void kernel_launch(void* const* d_in, const int* in_sizes, int n_in,
                              void* d_out, int out_size, void* d_ws,
                              size_t ws_size, hipStream_t stream) {
  (void)in_sizes; (void)n_in; (void)out_size;
  const float* h = (const float*)d_in[0];
  const int* adj = (const int*)d_in[1];
  const float* W = (const float*)d_in[2];
  const float* a = (const float*)d_in[3];
  float* out = (float*)d_out;
  char* ws = (char*)d_ws;

  unsigned short* gTs = (unsigned short*)ws;               // 2 MB (swizzled)
  float4* spack = (float4*)(ws + (size_t)NN * CC * 2);     // 512 KB
  float* dtc = (float*)(spack + (size_t)NH * NN);          // 256 KB (2 planes)
  unsigned int* adjb =
      (unsigned int*)(dtc + (size_t)(NN / 32) * 512);      // 2 MB
  char* after = (char*)(adjb + (size_t)NN * NW32);
  const size_t base = (size_t)(after - ws);
  const size_t per_split = (size_t)NN * CC * 4 + (size_t)NH * NN * 4;

  int splits = 1;
  if (ws_size >= base + 8 * per_split) splits = 8;
  else if (ws_size >= base + 4 * per_split) splits = 4;
  else if (ws_size >= base + 2 * per_split) splits = 2;

  k_gemm<<<GEMM_BLKS + BP_BLKS, 256, 0, stream>>>(h, W, a, adj, adjb, gTs,
                                                  spack, dtc);

  const int nblk = (NN / 32) * splits;
  if (splits == 1) {
    k_attn<<<nblk, 256, 0, stream>>>(adjb, gTs, spack, dtc, nullptr, nullptr,
                                     out, 1, 1);
  } else {
    float* acc_ws = (float*)after;
    float* l_ws = acc_ws + (size_t)splits * NN * CC;
    k_attn<<<nblk, 256, 0, stream>>>(adjb, gTs, spack, dtc, acc_ws, l_ws, out,
                                     splits, 0);
    k_combine<<<NN * CC / 4 / 256, 256, 0, stream>>>(acc_ws, l_ws, out,
                                                     splits);
  }
}

// Round 12
// 72.404 us; speedup vs baseline: 1.5580x; 1.2114x over previous
//
#include <hip/hip_runtime.h>

#define NN 4096
#define FIN 256
#define CC 256
#define NH 8
#define NW32 (NN / 32)  // u32 words per adj row

typedef __attribute__((ext_vector_type(8))) short short8;
typedef __attribute__((ext_vector_type(4))) float f32x4;
typedef __attribute__((ext_vector_type(4))) unsigned int u32x4;

__device__ __forceinline__ unsigned cvtpk_bf16(float lo, float hi) {
  unsigned r;
  asm("v_cvt_pk_bf16_f32 %0, %1, %2" : "=v"(r) : "v"(lo), "v"(hi));
  return r;
}

__device__ __forceinline__ unsigned short bf16rn(float x) {
  unsigned int u = __builtin_bit_cast(unsigned int, x);
  u += 0x7fffu + ((u >> 16) & 1u);
  return (unsigned short)(u >> 16);
}

__device__ __forceinline__ void gl_lds16(const void* g, void* l) {
  __builtin_amdgcn_global_load_lds(
      (const __attribute__((address_space(1))) void*)g,
      (__attribute__((address_space(3))) void*)l, 16, 0, 0);
}

// ---------------- K1: fused {GEMM+epilogue | adj bitpack} by block range ---
// blocks [0,512): GEMM g=h@W, write swizzled gTs + spack + dtc.
// blocks [512, 512+2048): bitpack — thread => one u32 word (32 contiguous
//   adj ints, 128 B) via 8 independent int4 loads (ILP=8, streaming).
// adjb[i][w] bit e = adj[i][w*32+e]!=0.
// gTs: chunk-major SWIZZLED bf16 (unit 16B at [jc][c][p], p = q ^ ((c>>1)&3)).
// spack[h][n] = (e^s_src, e^{0.2 s_src}, 0, 0).
// dtc[jc][2][NH][32] = (e^sd, e^{0.2 sd}).
#define GROWS 8
#define GEMM_BLKS (NN / GROWS)                  // 512
#define BP_BLKS (NN * NW32 / 256)               // 2048
__global__ __launch_bounds__(256) void k_gemm(
    const float* __restrict__ h, const float* __restrict__ W,
    const float* __restrict__ a, const int* __restrict__ adj,
    unsigned int* __restrict__ adjb, unsigned short* __restrict__ gTs,
    float4* __restrict__ spack, float* __restrict__ dtc) {
  __shared__ float hs[GROWS][FIN];
  const int t = threadIdx.x;
  const int bx = blockIdx.x;

  if (bx >= GEMM_BLKS) {
    // ---- bitpack path: one word per thread, 8x int4 streaming loads ----
    const int wid = (bx - GEMM_BLKS) * 256 + t;  // word index
    const int row = wid >> 7, wd = wid & 127;
    const int* src = adj + (size_t)row * NN + wd * 32;
    int4 v[8];
#pragma unroll
    for (int s = 0; s < 8; ++s) v[s] = *(const int4*)&src[s * 4];
    unsigned int bits = 0;
#pragma unroll
    for (int s = 0; s < 8; ++s) {
      bits |= (v[s].x ? 1u : 0u) << (s * 4 + 0);
      bits |= (v[s].y ? 1u : 0u) << (s * 4 + 1);
      bits |= (v[s].z ? 1u : 0u) << (s * 4 + 2);
      bits |= (v[s].w ? 1u : 0u) << (s * 4 + 3);
    }
    adjb[(size_t)row * NW32 + wd] = bits;
    return;
  }

  // ---- GEMM path ----
  const int r0 = bx * GROWS;
#pragma unroll
  for (int idx = t; idx < GROWS * FIN / 4; idx += 256) {
    const int r = idx >> 6, c4 = idx & 63;
    *(float4*)&hs[r][c4 * 4] =
        *(const float4*)&h[(size_t)(r0 + r) * FIN + c4 * 4];
  }
  __syncthreads();
  const int c = t;
  float acc[GROWS];
#pragma unroll
  for (int r = 0; r < GROWS; ++r) acc[r] = 0.f;
  for (int k = 0; k < FIN; k += 4) {
    const float w0 = W[(size_t)(k + 0) * CC + c];
    const float w1 = W[(size_t)(k + 1) * CC + c];
    const float w2 = W[(size_t)(k + 2) * CC + c];
    const float w3 = W[(size_t)(k + 3) * CC + c];
#pragma unroll
    for (int r = 0; r < GROWS; ++r) {
      const float4 hv = *(const float4*)&hs[r][k];
      acc[r] += hv.x * w0 + hv.y * w1 + hv.z * w2 + hv.w * w3;
    }
  }
  const int f = c & 31, hh = c >> 5;
  const float aS = a[f], aD = a[32 + f];
  unsigned short gu[GROWS];
#pragma unroll
  for (int r = 0; r < GROWS; ++r) {
    float ps = acc[r] * aS, pd = acc[r] * aD;
#pragma unroll
    for (int m = 1; m < 32; m <<= 1) {
      ps += __shfl_xor(ps, m, 64);
      pd += __shfl_xor(pd, m, 64);
    }
    if (f == 0) {
      const int n = r0 + r;
      spack[(size_t)hh * NN + n] =
          make_float4(__expf(ps), __expf(0.2f * ps), 0.f, 0.f);
      float* dc = dtc + (size_t)(n >> 5) * 512 + hh * 32 + (n & 31);
      dc[0] = __expf(pd);
      dc[256] = __expf(0.2f * pd);
    }
    gu[r] = bf16rn(acc[r]);
  }
  uint4 gv;
  gv.x = (unsigned)gu[0] | ((unsigned)gu[1] << 16);
  gv.y = (unsigned)gu[2] | ((unsigned)gu[3] << 16);
  gv.z = (unsigned)gu[4] | ((unsigned)gu[5] << 16);
  gv.w = (unsigned)gu[6] | ((unsigned)gu[7] << 16);
  const int jc = r0 >> 5, qq = (r0 >> 3) & 3;
  const int p = qq ^ ((c >> 1) & 3);
  *(uint4*)(gTs + ((size_t)jc * 1024 + c * 4 + p) * 8) = gv;
}

// ---------------- K2: LDS 2-phase (JB=64) fused masked-softmax + MFMA PV ---
// Block = 64 i x 8 heads; 4 waves: wave w -> (i-half = w>>1, head-quad = w&1).
// Buffer = 64 j (2 sub-chunks of 32): gt 32KB (swizzled) + dt 4KB; dbuf 72KB.
// e^leaky(ss+sd) = max(e^ss*e^sd, e^{0.2ss}*e^{0.2sd})  (exact identity).
struct Buf {
  unsigned short gt[2][8192];  // 32 KB: [sub][unit u = c*4 + (q^((c>>1)&3))]
  float dt[2][2][NH][32];      // 4 KB:  [sub][plane][h][j]
};

__global__ __launch_bounds__(256, 2) void k_attn(
    const unsigned int* __restrict__ adjb, const unsigned short* __restrict__ gTs,
    const float4* __restrict__ spack, const float* __restrict__ dtc,
    float* __restrict__ acc_ws, float* __restrict__ l_ws,
    float* __restrict__ out, const int splits, const int direct) {
  __shared__ Buf buf[2];  // 72 KB

  const int lane = threadIdx.x & 63;
  const int w = threadIdx.x >> 6;
  const int il = lane & 15, q = lane >> 4;
  const int bx = blockIdx.x;
  const int sp = bx & (splits - 1);
  const int ib = bx / splits;
  const int i0w = ib * 64 + (w >> 1) * 32;  // this wave's 32 i-rows
  const int hquad = w & 1;                  // heads hquad*4 .. +3
  const int jrange = NN / splits, j0b = sp * jrange;
  const int c0 = j0b >> 5;                  // first 32-chunk index

  // hoisted i-side scalars (4 heads x 2 it)
  float e1v[4][2], e2v[4][2];
#pragma unroll
  for (int hp = 0; hp < 4; ++hp)
#pragma unroll
    for (int it = 0; it < 2; ++it) {
      const float4 v =
          spack[(size_t)(hquad * 4 + hp) * NN + i0w + it * 16 + il];
      e1v[hp][it] = v.x; e2v[hp][it] = v.y;
    }

  f32x4 acc[4][2][2];
  f32x4 lac[4][2];
#pragma unroll
  for (int hp = 0; hp < 4; ++hp)
#pragma unroll
    for (int it = 0; it < 2; ++it) {
#pragma unroll
      for (int r = 0; r < 4; ++r) lac[hp][it][r] = 0.f;
#pragma unroll
      for (int ft = 0; ft < 2; ++ft)
#pragma unroll
        for (int r = 0; r < 4; ++r) acc[hp][it][ft][r] = 0.f;
    }

  const short8 ones = {(short)0x3F80, (short)0x3F80, (short)0x3F80,
                       (short)0x3F80, (short)0x3F80, (short)0x3F80,
                       (short)0x3F80, (short)0x3F80};

  // bitpacked adj: one u64 per row per 64-j buffer
  const unsigned long long* ab0 =
      (const unsigned long long*)(adjb + (size_t)(i0w + il) * NW32) +
      (j0b >> 6);
  const unsigned long long* ab1 =
      (const unsigned long long*)(adjb + (size_t)(i0w + 16 + il) * NW32) +
      (j0b >> 6);
  const int sh = q * 8;
  const int pswz = q ^ ((il >> 1) & 3);

  // ---- staging: linear copies (gTs pre-swizzled in global) ----
  auto stage = [&](Buf* b, int jb) {
    const unsigned short* src = gTs + (size_t)(c0 + jb * 2) * 8192;
#pragma unroll
    for (int pass = 0; pass < 8; ++pass) {
      const int base = pass * 256 + w * 64;  // wave-uniform
      gl_lds16(src + (size_t)(base + lane) * 8, (char*)&b->gt[0][0] + base * 16);
    }
    const float* dsrc = dtc + (size_t)(c0 + jb * 2) * 512;
    gl_lds16(dsrc + (size_t)(w * 64 + lane) * 4,
             (char*)&b->dt[0][0][0][0] + (w * 64) * 16);
  };

  const int nbuf = jrange / 64;
  stage(&buf[0], 0);
  unsigned long long pb0 = ab0[0], pb1 = ab1[0];
  __syncthreads();
  int cur = 0;

  for (int jb = 0; jb < nbuf; ++jb) {
    if (jb + 1 < nbuf) stage(&buf[cur ^ 1], jb + 1);
    const Buf* bc = &buf[cur];
    const unsigned int bl0[2] = {(unsigned int)pb0, (unsigned int)(pb0 >> 32)};
    const unsigned int bl1[2] = {(unsigned int)pb1, (unsigned int)(pb1 >> 32)};
    if (jb + 1 < nbuf) { pb0 = ab0[jb + 1]; pb1 = ab1[jb + 1]; }

#pragma unroll
    for (int sub = 0; sub < 2; ++sub) {
      float adf[2][8];
#pragma unroll
      for (int e = 0; e < 8; ++e) {
        adf[0][e] = (float)((bl0[sub] >> (sh + e)) & 1u);
        adf[1][e] = (float)((bl1[sub] >> (sh + e)) & 1u);
      }
#pragma unroll
      for (int hp = 0; hp < 4; ++hp) {
        const int hh = hquad * 4 + hp;
        float e1j[8], e2j[8];
        *(float4*)&e1j[0] = *(const float4*)&bc->dt[sub][0][hh][q * 8];
        *(float4*)&e1j[4] = *(const float4*)&bc->dt[sub][0][hh][q * 8 + 4];
        *(float4*)&e2j[0] = *(const float4*)&bc->dt[sub][1][hh][q * 8];
        *(float4*)&e2j[4] = *(const float4*)&bc->dt[sub][1][hh][q * 8 + 4];
        const int u0 = (hh * 32 + il) * 4 + pswz;
        const short8 b0 = *(const short8*)&bc->gt[sub][u0 * 8];
        const short8 b1 = *(const short8*)&bc->gt[sub][(u0 + 64) * 8];
#pragma unroll
        for (int it = 0; it < 2; ++it) {
          const float ei1 = e1v[hp][it], ei2 = e2v[hp][it];
          float wv[8];
#pragma unroll
          for (int e = 0; e < 8; ++e)
            wv[e] = fmaxf(ei1 * e1j[e], ei2 * e2j[e]) * adf[it][e];
          u32x4 uu;
#pragma unroll
          for (int m = 0; m < 4; ++m)
            uu[m] = cvtpk_bf16(wv[2 * m], wv[2 * m + 1]);
          const short8 afr = __builtin_bit_cast(short8, uu);
          acc[hp][it][0] = __builtin_amdgcn_mfma_f32_16x16x32_bf16(
              afr, b0, acc[hp][it][0], 0, 0, 0);
          acc[hp][it][1] = __builtin_amdgcn_mfma_f32_16x16x32_bf16(
              afr, b1, acc[hp][it][1], 0, 0, 0);
          lac[hp][it] = __builtin_amdgcn_mfma_f32_16x16x32_bf16(
              afr, ones, lac[hp][it], 0, 0, 0);
        }
      }
    }
    __syncthreads();  // drains staging vmcnt + read lgkm; swap safe
    cur ^= 1;
  }

  if (direct) {
#pragma unroll
    for (int hp = 0; hp < 4; ++hp) {
      const int hh = hquad * 4 + hp;
#pragma unroll
      for (int it = 0; it < 2; ++it)
#pragma unroll
        for (int r = 0; r < 4; ++r) {
          const float inv = 1.f / lac[hp][it][r];
          const size_t irow = i0w + it * 16 + q * 4 + r;
#pragma unroll
          for (int ft = 0; ft < 2; ++ft)
            out[irow * CC + hh * 32 + ft * 16 + il] =
                acc[hp][it][ft][r] * inv;
        }
    }
  } else {
#pragma unroll
    for (int hp = 0; hp < 4; ++hp) {
      const int hh = hquad * 4 + hp;
#pragma unroll
      for (int it = 0; it < 2; ++it)
#pragma unroll
        for (int r = 0; r < 4; ++r) {
          const size_t irow = i0w + it * 16 + q * 4 + r;
          if (il == 0)
            l_ws[((size_t)sp * NH + hh) * NN + irow] = lac[hp][it][r];
#pragma unroll
          for (int ft = 0; ft < 2; ++ft)
            acc_ws[((size_t)sp * NN + irow) * CC + hh * 32 + ft * 16 + il] =
                acc[hp][it][ft][r];
        }
    }
  }
}

// ---------------- K3: combine split partials ----------------
__global__ __launch_bounds__(256) void k_combine(
    const float* __restrict__ acc_ws, const float* __restrict__ l_ws,
    float* __restrict__ out, const int splits) {
  const int idx = blockIdx.x * 256 + threadIdx.x;  // float4 index
  const int row = idx >> 6, c4 = idx & 63;
  const int hh = c4 >> 3;
  float ax = 0.f, ay = 0.f, az = 0.f, aw = 0.f, l = 0.f;
  for (int s = 0; s < splits; ++s) {
    const float4 v =
        *(const float4*)&acc_ws[((size_t)s * NN + row) * CC + c4 * 4];
    ax += v.x; ay += v.y; az += v.z; aw += v.w;
    l += l_ws[((size_t)s * NH + hh) * NN + row];
  }
  const float inv = 1.f / l;
  *(float4*)&out[(size_t)row * CC + c4 * 4] =
      make_float4(ax * inv, ay * inv, az * inv, aw * inv);
}

extern "C" void kernel_launch(void* const* d_in, const int* in_sizes, int n_in,
                              void* d_out, int out_size, void* d_ws,
                              size_t ws_size, hipStream_t stream) {
  (void)in_sizes; (void)n_in; (void)out_size;
  const float* h = (const float*)d_in[0];
  const int* adj = (const int*)d_in[1];
  const float* W = (const float*)d_in[2];
  const float* a = (const float*)d_in[3];
  float* out = (float*)d_out;
  char* ws = (char*)d_ws;

  unsigned short* gTs = (unsigned short*)ws;               // 2 MB (swizzled)
  float4* spack = (float4*)(ws + (size_t)NN * CC * 2);     // 512 KB
  float* dtc = (float*)(spack + (size_t)NH * NN);          // 256 KB (2 planes)
  unsigned int* adjb =
      (unsigned int*)(dtc + (size_t)(NN / 32) * 512);      // 2 MB
  char* after = (char*)(adjb + (size_t)NN * NW32);
  const size_t base = (size_t)(after - ws);
  const size_t per_split = (size_t)NN * CC * 4 + (size_t)NH * NN * 4;

  int splits = 1;
  if (ws_size >= base + 8 * per_split) splits = 8;
  else if (ws_size >= base + 4 * per_split) splits = 4;
  else if (ws_size >= base + 2 * per_split) splits = 2;

  k_gemm<<<GEMM_BLKS + BP_BLKS, 256, 0, stream>>>(h, W, a, adj, adjb, gTs,
                                                  spack, dtc);

  const int nblk = (NN / 64) * splits;
  if (splits == 1) {
    k_attn<<<nblk, 256, 0, stream>>>(adjb, gTs, spack, dtc, nullptr, nullptr,
                                     out, 1, 1);
  } else {
    float* acc_ws = (float*)after;
    float* l_ws = acc_ws + (size_t)splits * NN * CC;
    k_attn<<<nblk, 256, 0, stream>>>(adjb, gTs, spack, dtc, acc_ws, l_ws, out,
                                     splits, 0);
    k_combine<<<NN * CC / 4 / 256, 256, 0, stream>>>(acc_ws, l_ws, out,
                                                     splits);
  }
}

// Round 13
// 69.731 us; speedup vs baseline: 1.6177x; 1.0383x over previous
//
#include <hip/hip_runtime.h>

#define NN 4096
#define FIN 256
#define CC 256
#define NH 8
#define NW32 (NN / 32)  // u32 words per adj row

typedef __attribute__((ext_vector_type(8))) short short8;
typedef __attribute__((ext_vector_type(4))) float f32x4;
typedef __attribute__((ext_vector_type(4))) unsigned int u32x4;

__device__ __forceinline__ unsigned cvtpk_bf16(float lo, float hi) {
  unsigned r;
  asm("v_cvt_pk_bf16_f32 %0, %1, %2" : "=v"(r) : "v"(lo), "v"(hi));
  return r;
}

__device__ __forceinline__ unsigned short bf16rn(float x) {
  unsigned int u = __builtin_bit_cast(unsigned int, x);
  u += 0x7fffu + ((u >> 16) & 1u);
  return (unsigned short)(u >> 16);
}

__device__ __forceinline__ void gl_lds16(const void* g, void* l) {
  __builtin_amdgcn_global_load_lds(
      (const __attribute__((address_space(1))) void*)g,
      (__attribute__((address_space(3))) void*)l, 16, 0, 0);
}

// ---------------- K1: fused {GEMM+epilogue | adj bitpack} by block range ---
// blocks [0,512): GEMM g=h@W -> swizzled gTs + spack + dtc.
// blocks [512, 512+2048): bitpack (one u32 word per thread, 8x int4 stream).
// adjb[i][w] bit e = adj[i][w*32+e]!=0.
// gTs: chunk-major SWIZZLED bf16 (16B unit at [jc][c][p], p = q ^ ((c>>1)&3)).
// spack[h][n] = (e^s_src, e^{0.2 s_src}, 0, 0).
// dtc[jc][h][plane][32] = (e^sd, e^{0.2 sd})  (head-sliceable).
#define GROWS 8
#define GEMM_BLKS (NN / GROWS)                  // 512
#define BP_BLKS (NN * NW32 / 256)               // 2048
__global__ __launch_bounds__(256) void k_gemm(
    const float* __restrict__ h, const float* __restrict__ W,
    const float* __restrict__ a, const int* __restrict__ adj,
    unsigned int* __restrict__ adjb, unsigned short* __restrict__ gTs,
    float4* __restrict__ spack, float* __restrict__ dtc) {
  __shared__ float hs[GROWS][FIN];
  const int t = threadIdx.x;
  const int bx = blockIdx.x;

  if (bx >= GEMM_BLKS) {
    const int wid = (bx - GEMM_BLKS) * 256 + t;  // word index
    const int row = wid >> 7, wd = wid & 127;
    const int* src = adj + (size_t)row * NN + wd * 32;
    int4 v[8];
#pragma unroll
    for (int s = 0; s < 8; ++s) v[s] = *(const int4*)&src[s * 4];
    unsigned int bits = 0;
#pragma unroll
    for (int s = 0; s < 8; ++s) {
      bits |= (v[s].x ? 1u : 0u) << (s * 4 + 0);
      bits |= (v[s].y ? 1u : 0u) << (s * 4 + 1);
      bits |= (v[s].z ? 1u : 0u) << (s * 4 + 2);
      bits |= (v[s].w ? 1u : 0u) << (s * 4 + 3);
    }
    adjb[(size_t)row * NW32 + wd] = bits;
    return;
  }

  // ---- GEMM path ----
  const int r0 = bx * GROWS;
#pragma unroll
  for (int idx = t; idx < GROWS * FIN / 4; idx += 256) {
    const int r = idx >> 6, c4 = idx & 63;
    *(float4*)&hs[r][c4 * 4] =
        *(const float4*)&h[(size_t)(r0 + r) * FIN + c4 * 4];
  }
  __syncthreads();
  const int c = t;
  float acc[GROWS];
#pragma unroll
  for (int r = 0; r < GROWS; ++r) acc[r] = 0.f;
  for (int k = 0; k < FIN; k += 4) {
    const float w0 = W[(size_t)(k + 0) * CC + c];
    const float w1 = W[(size_t)(k + 1) * CC + c];
    const float w2 = W[(size_t)(k + 2) * CC + c];
    const float w3 = W[(size_t)(k + 3) * CC + c];
#pragma unroll
    for (int r = 0; r < GROWS; ++r) {
      const float4 hv = *(const float4*)&hs[r][k];
      acc[r] += hv.x * w0 + hv.y * w1 + hv.z * w2 + hv.w * w3;
    }
  }
  const int f = c & 31, hh = c >> 5;
  const float aS = a[f], aD = a[32 + f];
  unsigned short gu[GROWS];
#pragma unroll
  for (int r = 0; r < GROWS; ++r) {
    float ps = acc[r] * aS, pd = acc[r] * aD;
#pragma unroll
    for (int m = 1; m < 32; m <<= 1) {
      ps += __shfl_xor(ps, m, 64);
      pd += __shfl_xor(pd, m, 64);
    }
    if (f == 0) {
      const int n = r0 + r;
      spack[(size_t)hh * NN + n] =
          make_float4(__expf(ps), __expf(0.2f * ps), 0.f, 0.f);
      float* dc = dtc + ((size_t)(n >> 5) * NH + hh) * 64 + (n & 31);
      dc[0] = __expf(pd);
      dc[32] = __expf(0.2f * pd);
    }
    gu[r] = bf16rn(acc[r]);
  }
  uint4 gv;
  gv.x = (unsigned)gu[0] | ((unsigned)gu[1] << 16);
  gv.y = (unsigned)gu[2] | ((unsigned)gu[3] << 16);
  gv.z = (unsigned)gu[4] | ((unsigned)gu[5] << 16);
  gv.w = (unsigned)gu[6] | ((unsigned)gu[7] << 16);
  const int jc = r0 >> 5, qq = (r0 >> 3) & 3;
  const int p = qq ^ ((c >> 1) & 3);
  *(uint4*)(gTs + ((size_t)jc * 1024 + c * 4 + p) * 8) = gv;
}

// ---------------- K2: LDS 2-phase (JB=64) fused masked-softmax + MFMA PV ---
// Block = 128 i x 2 heads; 4 waves = 4 i-quarters sharing the head-pair ->
// staged gt (4KB/sub, swizzled slice) read by ALL waves (4x reuse).
// e^leaky(ss+sd) = max(e^ss*e^sd, e^{0.2ss}*e^{0.2sd})  (exact identity).
struct Buf {
  unsigned short gt[2][2048];  // 8 KB: [sub][unit u = relc*4 + (q^((relc>>1)&3))]
  float dt[2][2][2][32];       // 1 KB: [sub][hrel][plane][j]
};

__global__ __launch_bounds__(256, 2) void k_attn(
    const unsigned int* __restrict__ adjb, const unsigned short* __restrict__ gTs,
    const float4* __restrict__ spack, const float* __restrict__ dtc,
    float* __restrict__ acc_ws, float* __restrict__ l_ws,
    float* __restrict__ out, const int splits, const int direct) {
  __shared__ Buf buf[2];  // 18 KB

  const int lane = threadIdx.x & 63;
  const int w = threadIdx.x >> 6;
  const int il = lane & 15, q = lane >> 4;
  const int bx = blockIdx.x;
  const int sp = bx & (splits - 1);
  const int rest = bx / splits;
  const int hg = rest & 3;                  // head-group: heads {2hg, 2hg+1}
  const int ib = rest >> 2;
  const int i0w = ib * 128 + w * 32;        // this wave's 32 i-rows
  const int jrange = NN / splits, j0b = sp * jrange;
  const int c0 = j0b >> 5;                  // first 32-chunk index

  // hoisted i-side scalars (2 heads x 2 it)
  float e1v[2][2], e2v[2][2];
#pragma unroll
  for (int hp = 0; hp < 2; ++hp)
#pragma unroll
    for (int it = 0; it < 2; ++it) {
      const float4 v = spack[(size_t)(hg * 2 + hp) * NN + i0w + it * 16 + il];
      e1v[hp][it] = v.x; e2v[hp][it] = v.y;
    }

  f32x4 acc[2][2][2];
  f32x4 lac[2][2];
#pragma unroll
  for (int hp = 0; hp < 2; ++hp)
#pragma unroll
    for (int it = 0; it < 2; ++it) {
#pragma unroll
      for (int r = 0; r < 4; ++r) lac[hp][it][r] = 0.f;
#pragma unroll
      for (int ft = 0; ft < 2; ++ft)
#pragma unroll
        for (int r = 0; r < 4; ++r) acc[hp][it][ft][r] = 0.f;
    }

  const short8 ones = {(short)0x3F80, (short)0x3F80, (short)0x3F80,
                       (short)0x3F80, (short)0x3F80, (short)0x3F80,
                       (short)0x3F80, (short)0x3F80};

  // bitpacked adj: one u64 per row per 64-j buffer
  const unsigned long long* ab0 =
      (const unsigned long long*)(adjb + (size_t)(i0w + il) * NW32) +
      (j0b >> 6);
  const unsigned long long* ab1 =
      (const unsigned long long*)(adjb + (size_t)(i0w + 16 + il) * NW32) +
      (j0b >> 6);
  const int sh = q * 8;
  const int pswz = q ^ ((il >> 1) & 3);

  // ---- staging: linear gt slice (pre-swizzled) + dt head-slice ----
  auto stage = [&](Buf* b, int jb) {
#pragma unroll
    for (int sub = 0; sub < 2; ++sub) {
      const unsigned short* src =
          gTs + ((size_t)(c0 + jb * 2 + sub) * 1024 + hg * 256 + w * 64) * 8;
      gl_lds16(src + (size_t)lane * 8, (char*)&b->gt[sub][0] + (w * 64) * 16);
    }
    if (w == 0) {
      // lane -> sub=lane>>5, hrel=(lane>>4)&1, plane=(lane>>3)&1, j0=(lane&7)*4
      const float* dsrc =
          dtc +
          ((size_t)(c0 + jb * 2 + (lane >> 5)) * NH + hg * 2 + ((lane >> 4) & 1)) *
              64 +
          ((lane >> 3) & 1) * 32 + (lane & 7) * 4;
      gl_lds16(dsrc, (char*)&b->dt[0][0][0][0]);
    }
  };

  const int nbuf = jrange / 64;
  stage(&buf[0], 0);
  unsigned long long pb0 = ab0[0], pb1 = ab1[0];
  __syncthreads();
  int cur = 0;

  for (int jb = 0; jb < nbuf; ++jb) {
    if (jb + 1 < nbuf) stage(&buf[cur ^ 1], jb + 1);
    const Buf* bc = &buf[cur];
    const unsigned int bl0[2] = {(unsigned int)pb0, (unsigned int)(pb0 >> 32)};
    const unsigned int bl1[2] = {(unsigned int)pb1, (unsigned int)(pb1 >> 32)};
    if (jb + 1 < nbuf) { pb0 = ab0[jb + 1]; pb1 = ab1[jb + 1]; }

#pragma unroll
    for (int sub = 0; sub < 2; ++sub) {
      float adf[2][8];
#pragma unroll
      for (int e = 0; e < 8; ++e) {
        adf[0][e] = (float)((bl0[sub] >> (sh + e)) & 1u);
        adf[1][e] = (float)((bl1[sub] >> (sh + e)) & 1u);
      }
#pragma unroll
      for (int hp = 0; hp < 2; ++hp) {
        float e1j[8], e2j[8];
        *(float4*)&e1j[0] = *(const float4*)&bc->dt[sub][hp][0][q * 8];
        *(float4*)&e1j[4] = *(const float4*)&bc->dt[sub][hp][0][q * 8 + 4];
        *(float4*)&e2j[0] = *(const float4*)&bc->dt[sub][hp][1][q * 8];
        *(float4*)&e2j[4] = *(const float4*)&bc->dt[sub][hp][1][q * 8 + 4];
        const int u0 = (hp * 32 + il) * 4 + pswz;
        const short8 b0 = *(const short8*)&bc->gt[sub][u0 * 8];
        const short8 b1 = *(const short8*)&bc->gt[sub][(u0 + 64) * 8];
#pragma unroll
        for (int it = 0; it < 2; ++it) {
          const float ei1 = e1v[hp][it], ei2 = e2v[hp][it];
          float wv[8];
#pragma unroll
          for (int e = 0; e < 8; ++e)
            wv[e] = fmaxf(ei1 * e1j[e], ei2 * e2j[e]) * adf[it][e];
          u32x4 uu;
#pragma unroll
          for (int m = 0; m < 4; ++m)
            uu[m] = cvtpk_bf16(wv[2 * m], wv[2 * m + 1]);
          const short8 afr = __builtin_bit_cast(short8, uu);
          acc[hp][it][0] = __builtin_amdgcn_mfma_f32_16x16x32_bf16(
              afr, b0, acc[hp][it][0], 0, 0, 0);
          acc[hp][it][1] = __builtin_amdgcn_mfma_f32_16x16x32_bf16(
              afr, b1, acc[hp][it][1], 0, 0, 0);
          lac[hp][it] = __builtin_amdgcn_mfma_f32_16x16x32_bf16(
              afr, ones, lac[hp][it], 0, 0, 0);
        }
      }
    }
    __syncthreads();  // drains staging vmcnt + read lgkm; swap safe
    cur ^= 1;
  }

  if (direct) {
#pragma unroll
    for (int hp = 0; hp < 2; ++hp) {
      const int hh = hg * 2 + hp;
#pragma unroll
      for (int it = 0; it < 2; ++it)
#pragma unroll
        for (int r = 0; r < 4; ++r) {
          const float inv = 1.f / lac[hp][it][r];
          const size_t irow = i0w + it * 16 + q * 4 + r;
#pragma unroll
          for (int ft = 0; ft < 2; ++ft)
            out[irow * CC + hh * 32 + ft * 16 + il] =
                acc[hp][it][ft][r] * inv;
        }
    }
  } else {
#pragma unroll
    for (int hp = 0; hp < 2; ++hp) {
      const int hh = hg * 2 + hp;
#pragma unroll
      for (int it = 0; it < 2; ++it)
#pragma unroll
        for (int r = 0; r < 4; ++r) {
          const size_t irow = i0w + it * 16 + q * 4 + r;
          if (il == 0)
            l_ws[((size_t)sp * NH + hh) * NN + irow] = lac[hp][it][r];
#pragma unroll
          for (int ft = 0; ft < 2; ++ft)
            acc_ws[((size_t)sp * NN + irow) * CC + hh * 32 + ft * 16 + il] =
                acc[hp][it][ft][r];
        }
    }
  }
}

// ---------------- K3: combine split partials ----------------
__global__ __launch_bounds__(256) void k_combine(
    const float* __restrict__ acc_ws, const float* __restrict__ l_ws,
    float* __restrict__ out, const int splits) {
  const int idx = blockIdx.x * 256 + threadIdx.x;  // float4 index
  const int row = idx >> 6, c4 = idx & 63;
  const int hh = c4 >> 3;
  float ax = 0.f, ay = 0.f, az = 0.f, aw = 0.f, l = 0.f;
  for (int s = 0; s < splits; ++s) {
    const float4 v =
        *(const float4*)&acc_ws[((size_t)s * NN + row) * CC + c4 * 4];
    ax += v.x; ay += v.y; az += v.z; aw += v.w;
    l += l_ws[((size_t)s * NH + hh) * NN + row];
  }
  const float inv = 1.f / l;
  *(float4*)&out[(size_t)row * CC + c4 * 4] =
      make_float4(ax * inv, ay * inv, az * inv, aw * inv);
}

extern "C" void kernel_launch(void* const* d_in, const int* in_sizes, int n_in,
                              void* d_out, int out_size, void* d_ws,
                              size_t ws_size, hipStream_t stream) {
  (void)in_sizes; (void)n_in; (void)out_size;
  const float* h = (const float*)d_in[0];
  const int* adj = (const int*)d_in[1];
  const float* W = (const float*)d_in[2];
  const float* a = (const float*)d_in[3];
  float* out = (float*)d_out;
  char* ws = (char*)d_ws;

  unsigned short* gTs = (unsigned short*)ws;               // 2 MB (swizzled)
  float4* spack = (float4*)(ws + (size_t)NN * CC * 2);     // 512 KB
  float* dtc = (float*)(spack + (size_t)NH * NN);          // 256 KB
  unsigned int* adjb =
      (unsigned int*)(dtc + (size_t)(NN / 32) * NH * 64);  // 2 MB
  char* after = (char*)(adjb + (size_t)NN * NW32);
  const size_t base = (size_t)(after - ws);
  const size_t per_split = (size_t)NN * CC * 4 + (size_t)NH * NN * 4;

  int splits = 1;
  if (ws_size >= base + 8 * per_split) splits = 8;
  else if (ws_size >= base + 4 * per_split) splits = 4;
  else if (ws_size >= base + 2 * per_split) splits = 2;

  k_gemm<<<GEMM_BLKS + BP_BLKS, 256, 0, stream>>>(h, W, a, adj, adjb, gTs,
                                                  spack, dtc);

  const int nblk = (NN / 128) * 4 * splits;
  if (splits == 1) {
    k_attn<<<nblk, 256, 0, stream>>>(adjb, gTs, spack, dtc, nullptr, nullptr,
                                     out, 1, 1);
  } else {
    float* acc_ws = (float*)after;
    float* l_ws = acc_ws + (size_t)splits * NN * CC;
    k_attn<<<nblk, 256, 0, stream>>>(adjb, gTs, spack, dtc, acc_ws, l_ws, out,
                                     splits, 0);
    k_combine<<<NN * CC / 4 / 256, 256, 0, stream>>>(acc_ws, l_ws, out,
                                                     splits);
  }
}